// Round 6
// baseline (35.439 us; speedup 1.0000x reference)
//
#include <hip/hip_runtime.h>
#include <math.h>

#define SEQ 8192
#define HID 4096
#define TPB 1024
#define ROWS_PER_BLK (TPB / 64)        // 16 rows per block (1 row per wave)
#define NBLK (SEQ / ROWS_PER_BLK)      // 512 blocks = 2 blocks/CU, 32 waves/CU

// ---------------------------------------------------------------------------
// Fused matvec + softmax, fence-free cross-XCD protocol.
//   Phase 1: energies[r] = dot(eo[r,:], hidden[:]) — 1 wave/row, 16x
//     coalesced float4 loads/lane, shfl_xor reduce. Result published with an
//     AGENT-scope relaxed store (sc-bits: write-through to coherence point,
//     never dirty in a per-XCD L2 -> no wbl2/inv needed anywhere).
//   Ordering: raw `s_waitcnt vmcnt(0)` (wait only, NO cache maintenance —
//     Round 3 showed __threadfence()'s buffer_wbl2/inv per block collapses
//     the memory system 15x) before the AGENT-scope counter atomicAdd.
//   Phase 2: the block that sees counter==NBLK-1 reads all energies with
//     AGENT-scope loads (bypass stale L1/L2), softmaxes in-register, writes out.
// No spin-waits: every block reaches the atomicAdd unconditionally.
// ---------------------------------------------------------------------------
__global__ __launch_bounds__(TPB) void fused_attn_kernel(
    const float* __restrict__ hidden,     // [HID]
    const float* __restrict__ eo,         // [SEQ, HID]
    float* __restrict__ out,              // [SEQ]
    float* __restrict__ energies,         // ws: [SEQ]
    unsigned int* __restrict__ counter)   // ws: 1 uint, memset 0 per call
{
    const int tid  = threadIdx.x;
    const int lane = tid & 63;
    const int wid  = tid >> 6;            // 0..15
    const int row  = (int)blockIdx.x * ROWS_PER_BLK + wid;

    const float4* __restrict__ rp = (const float4*)(eo + (size_t)row * HID);
    const float4* __restrict__ hv = (const float4*)hidden;

    float acc = 0.0f;
#pragma unroll
    for (int k = 0; k < 16; ++k) {
        float4 a = rp[k * 64 + lane];     // HBM/L3 streaming
        float4 b = hv[k * 64 + lane];     // L1-resident after first touch
        acc = fmaf(a.x, b.x, acc);
        acc = fmaf(a.y, b.y, acc);
        acc = fmaf(a.z, b.z, acc);
        acc = fmaf(a.w, b.w, acc);
    }
#pragma unroll
    for (int off = 32; off > 0; off >>= 1)
        acc += __shfl_xor(acc, off, 64);

    if (lane == 0)
        __hip_atomic_store(&energies[row], acc,
                           __ATOMIC_RELAXED, __HIP_MEMORY_SCOPE_AGENT);

    // Wait for this wave's agent-scope store to be acked at the coherence
    // point. Pure wait — deliberately NOT __threadfence() (no cache ops).
    asm volatile("s_waitcnt vmcnt(0)" ::: "memory");
    __syncthreads();                      // all 16 waves' stores complete

    __shared__ int is_last;
    if (tid == 0) {
        unsigned int old = __hip_atomic_fetch_add(
            counter, 1u, __ATOMIC_RELAXED, __HIP_MEMORY_SCOPE_AGENT);
        is_last = (old == (unsigned)(NBLK - 1));
    }
    __syncthreads();
    if (!is_last) return;

    // ---- last block: softmax over all SEQ energies (agent-scope loads) ----
    __shared__ float redm[16];
    __shared__ float reds[16];

    float v[8];
    float m = -INFINITY;
#pragma unroll
    for (int i = 0; i < 8; ++i) {
        v[i] = __hip_atomic_load(&energies[i * TPB + tid],
                                 __ATOMIC_RELAXED, __HIP_MEMORY_SCOPE_AGENT);
        m = fmaxf(m, v[i]);
    }
#pragma unroll
    for (int off = 32; off > 0; off >>= 1)
        m = fmaxf(m, __shfl_xor(m, off, 64));
    if (lane == 0) redm[wid] = m;
    __syncthreads();
    float gmax = redm[0];
#pragma unroll
    for (int i = 1; i < 16; ++i) gmax = fmaxf(gmax, redm[i]);

    float s = 0.0f;
#pragma unroll
    for (int i = 0; i < 8; ++i) {
        v[i] = __expf(v[i] - gmax);
        s += v[i];
    }
#pragma unroll
    for (int off = 32; off > 0; off >>= 1)
        s += __shfl_xor(s, off, 64);
    if (lane == 0) reds[wid] = s;
    __syncthreads();
    float total = reds[0];
#pragma unroll
    for (int i = 1; i < 16; ++i) total += reds[i];
    const float inv = 1.0f / total;

#pragma unroll
    for (int i = 0; i < 8; ++i)
        out[i * TPB + tid] = v[i] * inv;  // coalesced scalar stores
}

extern "C" void kernel_launch(void* const* d_in, const int* in_sizes, int n_in,
                              void* d_out, int out_size, void* d_ws, size_t ws_size,
                              hipStream_t stream) {
    const float* hidden = (const float*)d_in[0];   // [1, 4096] fp32
    const float* eo     = (const float*)d_in[1];   // [8192, 4096] fp32
    float* out          = (float*)d_out;           // [1, 1, 8192] fp32
    float* energies     = (float*)d_ws;
    unsigned int* counter = (unsigned int*)((char*)d_ws + SEQ * sizeof(float));

    // zero the completion counter every call (graph-capturable memset node)
    hipMemsetAsync(counter, 0, sizeof(unsigned int), stream);
    fused_attn_kernel<<<NBLK, TPB, 0, stream>>>(hidden, eo, out, energies, counter);
}

// Round 7
// 28.310 us; speedup vs baseline: 1.2518x; 1.2518x over previous
//
#include <hip/hip_runtime.h>
#include <math.h>

#define SEQ 8192
#define HID 4096

// ---------------------------------------------------------------------------
// Kernel 1: energies[r] = dot(encoder_outputs[r, :], hidden[:])
// One 64-lane wave per row, 4 rows per 256-thread block, 2048 blocks =
// 8 blocks/CU. 16x fully-coalesced float4 loads per lane (1 KiB per
// instruction per wave); hidden is L1-resident after first touch.
// Measured ~23.5 us => ~5.7 TB/s effective read BW (~92% of the 6.3 TB/s
// copy-ubench ceiling). A/B history: LDS-staged hidden neutral (R4),
// 1024-thread blocks slower (R6), fusion with softmax slower (R3: fence
// L2-writeback storm 15x; R6: agent-scope uncached tail +7us).
// ---------------------------------------------------------------------------
__global__ __launch_bounds__(256) void matvec_kernel(
    const float* __restrict__ hidden,     // [HID]
    const float* __restrict__ eo,         // [SEQ, HID]
    float* __restrict__ energies)         // [SEQ]
{
    const int gwave = (blockIdx.x * blockDim.x + threadIdx.x) >> 6;  // row id
    const int lane  = threadIdx.x & 63;

    const float4* __restrict__ row = (const float4*)(eo + (size_t)gwave * HID);
    const float4* __restrict__ hv  = (const float4*)hidden;

    float acc = 0.0f;
#pragma unroll
    for (int k = 0; k < 16; ++k) {
        float4 a = row[k * 64 + lane];
        float4 b = hv [k * 64 + lane];
        acc = fmaf(a.x, b.x, acc);
        acc = fmaf(a.y, b.y, acc);
        acc = fmaf(a.z, b.z, acc);
        acc = fmaf(a.w, b.w, acc);
    }

#pragma unroll
    for (int off = 32; off > 0; off >>= 1)
        acc += __shfl_xor(acc, off, 64);
    if (lane == 0) energies[gwave] = acc;
}

// ---------------------------------------------------------------------------
// Kernel 2: out = softmax(energies) over SEQ. Single 256-thread block,
// 32 values/thread held in registers across the three passes.
// ---------------------------------------------------------------------------
__global__ __launch_bounds__(256) void softmax_kernel(
    const float* __restrict__ energies,   // [SEQ]
    float* __restrict__ out)              // [SEQ]
{
    __shared__ float red[8];
    const int tid  = threadIdx.x;
    const int wid  = tid >> 6;            // wave id 0..3
    const int lane = tid & 63;

    float v[32];
    float m = -INFINITY;
#pragma unroll
    for (int i = 0; i < 32; ++i) {
        v[i] = energies[i * 256 + tid];   // coalesced strided load
        m = fmaxf(m, v[i]);
    }
#pragma unroll
    for (int off = 32; off > 0; off >>= 1)
        m = fmaxf(m, __shfl_xor(m, off, 64));
    if (lane == 0) red[wid] = m;
    __syncthreads();
    const float gmax = fmaxf(fmaxf(red[0], red[1]), fmaxf(red[2], red[3]));

    float s = 0.0f;
#pragma unroll
    for (int i = 0; i < 32; ++i) {
        v[i] = __expf(v[i] - gmax);
        s += v[i];
    }
#pragma unroll
    for (int off = 32; off > 0; off >>= 1)
        s += __shfl_xor(s, off, 64);
    if (lane == 0) red[4 + wid] = s;      // distinct slots vs red[0..3]
    __syncthreads();
    const float total = (red[4] + red[5]) + (red[6] + red[7]);
    const float inv = 1.0f / total;

#pragma unroll
    for (int i = 0; i < 32; ++i)
        out[i * 256 + tid] = v[i] * inv;
}

extern "C" void kernel_launch(void* const* d_in, const int* in_sizes, int n_in,
                              void* d_out, int out_size, void* d_ws, size_t ws_size,
                              hipStream_t stream) {
    const float* hidden = (const float*)d_in[0];   // [1, 4096] fp32
    const float* eo     = (const float*)d_in[1];   // [8192, 4096] fp32
    float* out          = (float*)d_out;           // [1, 1, 8192] fp32
    float* energies     = (float*)d_ws;            // 8192 floats scratch

    matvec_kernel<<<SEQ / 4, 256, 0, stream>>>(hidden, eo, energies);
    softmax_kernel<<<1, 256, 0, stream>>>(energies, out);
}